// Round 11
// baseline (1786.278 us; speedup 1.0000x reference)
//
#include <hip/hip_runtime.h>
#include <hip/hip_bf16.h>

#define HID 128
#define NEG_SLOPE 0.2f
#define CSPLIT 8
#define KNN_CB 64
#define NCAND (CSPLIT * 12)   // 96 candidates per collider (3 per row-class per split)

typedef _Float16 f16x8 __attribute__((ext_vector_type(8)));
typedef float f32x4 __attribute__((ext_vector_type(4)));

// ---------- helpers ----------
__device__ __forceinline__ bool cand_lt(float d1, int i1, float d2, int i2) {
    return d1 < d2 || (d1 == d2 && i1 < i2);
}
__device__ __forceinline__ void ins3(float s, int r, float fd[3], int fi[3]) {
    if (!cand_lt(s, r, fd[2], fi[2])) return;
    if (cand_lt(s, r, fd[0], fi[0])) {
        fd[2]=fd[1];fi[2]=fi[1]; fd[1]=fd[0];fi[1]=fi[0]; fd[0]=s;fi[0]=r;
    } else if (cand_lt(s, r, fd[1], fi[1])) {
        fd[2]=fd[1];fi[2]=fi[1]; fd[1]=s;fi[1]=r;
    } else {
        fd[2]=s;fi[2]=r;
    }
}

// ---------- CSR build (also reused for NN pooling lists) ----------
__global__ void k_deg(const int* __restrict__ ei, int E, int n, int* __restrict__ deg) {
    int i = blockIdx.x * blockDim.x + threadIdx.x;
    if (i >= E + n) return;
    int d = (i < E) ? ei[E + i] : i - E;
    atomicAdd(&deg[d], 1);
}

__global__ void k_chunksum(const int* __restrict__ deg, int* __restrict__ bsum, int n) {
    int t = threadIdx.x;
    int i = blockIdx.x * 256 + t;
    int v = (i < n) ? deg[i] : 0;
#pragma unroll
    for (int o = 1; o < 64; o <<= 1) v += __shfl_xor(v, o);
    __shared__ int wsum[4];
    if ((t & 63) == 0) wsum[t >> 6] = v;
    __syncthreads();
    if (t == 0) bsum[blockIdx.x] = wsum[0] + wsum[1] + wsum[2] + wsum[3];
}

__global__ void k_scan_small(int* __restrict__ a, int nb) {
    __shared__ int buf[256];
    int t = threadIdx.x;
    int v = (t < nb) ? a[t] : 0;
    buf[t] = v;
    __syncthreads();
    for (int o = 1; o < 256; o <<= 1) {
        int add = (t >= o) ? buf[t - o] : 0;
        __syncthreads();
        buf[t] += add;
        __syncthreads();
    }
    if (t < nb) a[t] = buf[t] - v;
    if (t == 0) a[nb] = buf[nb - 1];
}

__global__ void k_scan_apply(const int* __restrict__ deg, const int* __restrict__ bsum,
                             int* __restrict__ off, int* __restrict__ cur, int n) {
    __shared__ int buf[256];
    int b = blockIdx.x, t = threadIdx.x;
    int i = b * 256 + t;
    int v = (i < n) ? deg[i] : 0;
    buf[t] = v;
    __syncthreads();
    for (int o = 1; o < 256; o <<= 1) {
        int add = (t >= o) ? buf[t - o] : 0;
        __syncthreads();
        buf[t] += add;
        __syncthreads();
    }
    int excl = bsum[b] + buf[t] - v;
    if (i < n) { off[i] = excl; cur[i] = excl; }
    if (b == 0 && t == 0) off[n] = bsum[gridDim.x];
}

__global__ void k_scatter(const int* __restrict__ ei, int E, int n,
                          int* __restrict__ cursor, int* __restrict__ csr) {
    int i = blockIdx.x * blockDim.x + threadIdx.x;
    if (i >= E + n) return;
    int s, d;
    if (i < E) { s = ei[i]; d = ei[E + i]; } else { s = d = i - E; }
    int pos = atomicAdd(&cursor[d], 1);
    csr[pos] = s;
}

// ---------- NN-pool list build ----------
__global__ void k_nn_hist(const int* __restrict__ nn, int m, int n_r, int* __restrict__ cnt) {
    int i = blockIdx.x * blockDim.x + threadIdx.x;
    if (i >= m) return;
    int r = nn[i];
    if ((unsigned)r < (unsigned)n_r) atomicAdd(&cnt[r], 1);
}

__global__ void k_nn_scatter(const int* __restrict__ nn, int m, int n_r,
                             int* __restrict__ cur, int* __restrict__ plist) {
    int i = blockIdx.x * blockDim.x + threadIdx.x;
    if (i >= m) return;
    int r = nn[i];
    if ((unsigned)r < (unsigned)n_r) {
        int pos = atomicAdd(&cur[r], 1);
        plist[pos] = i / 3;          // collider index
    }
}

// ---------- linear: 4 nodes per block (128 thr), W reads shared ----------
__global__ __launch_bounds__(128) void k_linear(
    const float* __restrict__ x, const float* __restrict__ W,
    const float* __restrict__ a_src, const float* __restrict__ a_dst,
    float* __restrict__ h, float* __restrict__ es, float* __restrict__ ed,
    int d_in, int n) {
    int n0 = blockIdx.x * 4;
    int t = threadIdx.x;
    int w = t >> 6, lane = t & 63;
    __shared__ float xs[4][HID];
    __shared__ float p1[2], p2[2];
#pragma unroll
    for (int u = 0; u < 4; ++u) {
        int node = n0 + u;
        if (t < d_in) xs[u][t] = (node < n) ? x[(size_t)node * d_in + t] : 0.f;
    }
    __syncthreads();
    float acc[4] = {0.f, 0.f, 0.f, 0.f};
    for (int k = 0; k < d_in; ++k) {
        float wv = W[k * HID + t];
#pragma unroll
        for (int u = 0; u < 4; ++u) acc[u] += xs[u][k] * wv;
    }
    float asv = a_src[t], adv = a_dst[t];
    for (int u = 0; u < 4; ++u) {
        int node = n0 + u;
        if (node >= n) break;                     // uniform across block
        h[(size_t)node * HID + t] = acc[u];
        float v1 = acc[u] * asv, v2 = acc[u] * adv;
#pragma unroll
        for (int o = 32; o > 0; o >>= 1) { v1 += __shfl_xor(v1, o); v2 += __shfl_xor(v2, o); }
        if (lane == 0) { p1[w] = v1; p2[w] = v2; }
        __syncthreads();
        if (t == 0) { es[node] = p1[0] + p1[1]; ed[node] = p2[0] + p2[1]; }
        __syncthreads();
    }
}

// ---------- fused GAT aggregation over CSR (wave per dst node) ----------
__global__ __launch_bounds__(256) void k_gat_csr(
    const int* __restrict__ off, const int* __restrict__ csr,
    const float* __restrict__ es, const float* __restrict__ ed,
    const float* __restrict__ h, const float* __restrict__ b,
    float* __restrict__ agg, int n,
    _Float16* __restrict__ h16, float* __restrict__ n2) {
    int node = blockIdx.x * 4 + (threadIdx.x >> 6);
    int lane = threadIdx.x & 63;
    if (node >= n) return;                        // wave-uniform
    int beg = off[node], end = off[node + 1];
    float edd = ed[node];
    float m = -INFINITY;
    for (int j = beg + lane; j < end; j += 64) {
        int s = csr[j];
        float e = es[s] + edd;
        e = e > 0.f ? e : NEG_SLOPE * e;
        m = fmaxf(m, e);
    }
#pragma unroll
    for (int o = 32; o > 0; o >>= 1) m = fmaxf(m, __shfl_xor(m, o));
    float den = 0.f, a0 = 0.f, a1 = 0.f;
    int j = beg;
    for (; j + 1 < end; j += 2) {
        int s0 = csr[j], s1 = csr[j + 1];
        float e0 = es[s0] + edd;
        float e1 = es[s1] + edd;
        e0 = e0 > 0.f ? e0 : NEG_SLOPE * e0;
        e1 = e1 > 0.f ? e1 : NEG_SLOPE * e1;
        float ex0 = expf(e0 - m);
        float ex1 = expf(e1 - m);
        float h00 = h[(size_t)s0 * HID + lane];
        float h01 = h[(size_t)s0 * HID + 64 + lane];
        float h10 = h[(size_t)s1 * HID + lane];
        float h11 = h[(size_t)s1 * HID + 64 + lane];
        den += ex0 + ex1;
        a0 += ex0 * h00 + ex1 * h10;
        a1 += ex0 * h01 + ex1 * h11;
    }
    if (j < end) {
        int s0 = csr[j];
        float e0 = es[s0] + edd;
        e0 = e0 > 0.f ? e0 : NEG_SLOPE * e0;
        float ex0 = expf(e0 - m);
        den += ex0;
        a0 += ex0 * h[(size_t)s0 * HID + lane];
        a1 += ex0 * h[(size_t)s0 * HID + 64 + lane];
    }
    float inv = 1.f / fmaxf(den, 1e-16f);
    float v0 = a0 * inv + b[lane];
    float v1 = a1 * inv + b[64 + lane];
    float r0 = v0 > 0.f ? v0 : 0.f;
    float r1 = v1 > 0.f ? v1 : 0.f;
    agg[(size_t)node * HID + lane] = r0;
    agg[(size_t)node * HID + 64 + lane] = r1;
    if (h16) {
        h16[(size_t)node * HID + lane] = (_Float16)r0;
        h16[(size_t)node * HID + 64 + lane] = (_Float16)r1;
    }
    if (n2) {
        float s2 = r0 * r0 + r1 * r1;
#pragma unroll
        for (int o = 32; o > 0; o >>= 1) s2 += __shfl_xor(s2, o);
        if (lane == 0) n2[node] = s2;
    }
}

// ---------- MFMA KNN scan ----------
__global__ __launch_bounds__(256) void k_knn_scan(
    const _Float16* __restrict__ hr2, const _Float16* __restrict__ hc2,
    const float* __restrict__ nr2, int n_c, int n_r, int rs_chunk,
    int* __restrict__ cand_i) {
    __shared__ _Float16 lds[2][64 * HID];
    int t = threadIdx.x, w = t >> 6, lane = t & 63;
    int li = lane & 15, q = lane >> 4;
    int c0 = blockIdx.x * KNN_CB;
    int split = blockIdx.y;
    int rbeg = split * rs_chunk;
    int rows = min(rs_chunk, n_r - rbeg);
    int rend = rbeg + rows;

    if (rows <= 0) {
        int c = c0 + w * 16 + li;
        if (c < n_c) {
            size_t base = ((size_t)(c * CSPLIT + split) * 4 + q) * 3;
            for (int k = 0; k < 3; ++k) cand_i[base + k] = 0x7fffffff;
        }
        return;
    }

    // B fragments: collider col = li, k = ks*32 + q*8 .. +7
    f16x8 bf[4];
    {
        int c = c0 + w * 16 + li;
        int cc = min(c, n_c - 1);
#pragma unroll
        for (int ks = 0; ks < 4; ++ks)
            bf[ks] = *(const f16x8*)(hc2 + (size_t)cc * HID + ks * 32 + q * 8);
    }

    float bd[3]; int bi[3];
#pragma unroll
    for (int k = 0; k < 3; ++k) { bd[k] = INFINITY; bi[k] = 0x7fffffff; }

    int nch = (rows + 63) >> 6;

    auto STAGE = [&](int bsel, int R) {
#pragma unroll
        for (int j = 0; j < 4; ++j) {
            int row = w * 16 + j * 4 + q;
            int gr = min(R + row, n_r - 1);
            int sslot = li ^ (row & 7);
            const _Float16* src = hr2 + (size_t)gr * HID + sslot * 8;
            _Float16* dst = &lds[bsel][(w * 16 + j * 4) * HID];  // wave-uniform
            __builtin_amdgcn_global_load_lds(
                (const __attribute__((address_space(1))) void*)src,
                (__attribute__((address_space(3))) void*)dst, 16, 0, 0);
        }
    };

    STAGE(0, rbeg);
    __syncthreads();

    for (int ch = 0; ch < nch; ++ch) {
        int cur = ch & 1;
        if (ch + 1 < nch) STAGE(cur ^ 1, rbeg + (ch + 1) * 64);  // prefetch
        int R = rbeg + ch * 64;
        const _Float16* buf = lds[cur];
        if (R + 64 <= rend) {
            float4 nrv[4];
#pragma unroll
            for (int tt = 0; tt < 4; ++tt)
                nrv[tt] = *(const float4*)(nr2 + R + tt * 16 + q * 4);
#pragma unroll
            for (int tt = 0; tt < 4; ++tt) {
                f32x4 a0 = {0.f, 0.f, 0.f, 0.f};
                int lr = tt * 16 + li;
                int swr = lr & 7;
#pragma unroll
                for (int ks = 0; ks < 4; ++ks) {
                    f16x8 af = *(const f16x8*)(&buf[lr * HID + (((ks * 4 + q) ^ swr) << 3)]);
                    a0 = __builtin_amdgcn_mfma_f32_16x16x32_f16(af, bf[ks], a0, 0, 0, 0);
                }
                int r_base = R + tt * 16 + q * 4;
                float sv[4] = {nrv[tt].x, nrv[tt].y, nrv[tt].z, nrv[tt].w};
#pragma unroll
                for (int i = 0; i < 4; ++i)
                    ins3(sv[i] - 2.f * a0[i], r_base + i, bd, bi);
            }
        } else {
            int rows_rem = rend - R;
#pragma unroll
            for (int tt = 0; tt < 4; ++tt) {
                int br = tt * 16;
                if (br < rows_rem) {
                    f32x4 a0 = {0.f, 0.f, 0.f, 0.f};
                    int lr = br + li;
                    int swr = lr & 7;
#pragma unroll
                    for (int ks = 0; ks < 4; ++ks) {
                        f16x8 af = *(const f16x8*)(&buf[lr * HID + (((ks * 4 + q) ^ swr) << 3)]);
                        a0 = __builtin_amdgcn_mfma_f32_16x16x32_f16(af, bf[ks], a0, 0, 0, 0);
                    }
                    int r_base = R + br + q * 4;
                    float4 nrv = *(const float4*)(nr2 + r_base);
                    float sv[4] = {nrv.x, nrv.y, nrv.z, nrv.w};
#pragma unroll
                    for (int i = 0; i < 4; ++i) {
                        int r = r_base + i;
                        if (r < rend) ins3(sv[i] - 2.f * a0[i], r, bd, bi);
                    }
                }
            }
        }
        __syncthreads();
    }

    {
        int c = c0 + w * 16 + li;
        if (c < n_c) {
            size_t base = ((size_t)(c * CSPLIT + split) * 4 + q) * 3;
#pragma unroll
            for (int k = 0; k < 3; ++k) cand_i[base + k] = bi[k];
        }
    }
}

// ---------- exact rerank: block per collider -> top-3 indices (NO atomics) ---
__global__ __launch_bounds__(256, 4) void k_rerank(
    const int* __restrict__ cand_i, const float* __restrict__ hc,
    const float* __restrict__ hr, const float* __restrict__ nr2,
    int n_r, int* __restrict__ nn_idx) {
    int c = blockIdx.x;
    int t = threadIdx.x;
    __shared__ float hcs[HID];
    __shared__ int ci[NCAND];
    __shared__ float sc[NCAND];
    __shared__ int scr[NCAND];
    if (t < HID) hcs[t] = hc[(size_t)c * HID + t];
    if (t < NCAND) {
        int r = cand_i[(size_t)c * NCAND + t];
        ci[t] = ((unsigned)r < (unsigned)n_r) ? r : -1;
    }
    __syncthreads();

    int k4 = t & 31;
    int g = t >> 5;                                // 0..7
    const float4* hr4 = (const float4*)hr;
    float4 a = ((const float4*)hcs)[k4];

    int rj[12];
    float4 v[12];
#pragma unroll
    for (int p = 0; p < 12; ++p) {                 // issue all loads (MLP)
        rj[p] = ci[p * 8 + g];
        v[p] = hr4[(size_t)max(rj[p], 0) * 32 + k4];
    }
    float fd[3] = {INFINITY, INFINITY, INFINITY};
    int fi[3] = {0x7fffffff, 0x7fffffff, 0x7fffffff};
#pragma unroll
    for (int p = 0; p < 12; ++p) {
        float d = a.x * v[p].x + a.y * v[p].y + a.z * v[p].z + a.w * v[p].w;
#pragma unroll
        for (int o = 1; o < 32; o <<= 1) d += __shfl_xor(d, o);
        if (k4 == 0) {
            int j = p * 8 + g;
            sc[j] = (rj[p] >= 0) ? nr2[rj[p]] - 2.f * d : INFINITY;
            scr[j] = (rj[p] >= 0) ? rj[p] : 0x7fffffff;
        }
    }
    __syncthreads();
    if (t < 64) {
        ins3(sc[t], scr[t], fd, fi);
        if (t < 32) ins3(sc[64 + t], scr[64 + t], fd, fi);
#pragma unroll
        for (int o = 1; o < 64; o <<= 1) {
            float sd0 = __shfl_xor(fd[0], o), sd1 = __shfl_xor(fd[1], o), sd2 = __shfl_xor(fd[2], o);
            int si0 = __shfl_xor(fi[0], o), si1 = __shfl_xor(fi[1], o), si2 = __shfl_xor(fi[2], o);
            ins3(sd0, si0, fd, fi);
            ins3(sd1, si1, fd, fi);
            ins3(sd2, si2, fd, fi);
        }
        if (t == 0) {
            nn_idx[c * 3 + 0] = fi[0];
            nn_idx[c * 3 + 1] = fi[1];
            nn_idx[c * 3 + 2] = fi[2];
        }
    }
}

// ---------- fused pooled-mean + decode (wave per resting node) ----------
// pooled[node] = mean of hc over colliders listing node among their top-3
// (gathered via plist CSR), then out = [hr, pooled] @ W_dec + b_dec.
__global__ __launch_bounds__(256) void k_pool_decode(
    const int* __restrict__ poff, const int* __restrict__ plist,
    const float* __restrict__ hc, const float* __restrict__ hr,
    const float* __restrict__ Wd, const float* __restrict__ bd,
    float* __restrict__ out, int n) {
    int node = blockIdx.x * 4 + (threadIdx.x >> 6);
    int lane = threadIdx.x & 63;
    if (node >= n) return;                        // wave-uniform
    int beg = poff[node], end = poff[node + 1];
    float p0 = 0.f, p1 = 0.f;
    for (int j = beg; j < end; ++j) {
        int c = plist[j];
        p0 += hc[(size_t)c * HID + lane];
        p1 += hc[(size_t)c * HID + 64 + lane];
    }
    float inv = 1.f / fmaxf((float)(end - beg), 1.f);
    p0 *= inv;
    p1 *= inv;
    float h0 = hr[(size_t)node * HID + lane];
    float h1 = hr[(size_t)node * HID + 64 + lane];
    float a0 = h0 * Wd[lane * 3 + 0] + h1 * Wd[(64 + lane) * 3 + 0]
             + p0 * Wd[(HID + lane) * 3 + 0] + p1 * Wd[(HID + 64 + lane) * 3 + 0];
    float a1 = h0 * Wd[lane * 3 + 1] + h1 * Wd[(64 + lane) * 3 + 1]
             + p0 * Wd[(HID + lane) * 3 + 1] + p1 * Wd[(HID + 64 + lane) * 3 + 1];
    float a2 = h0 * Wd[lane * 3 + 2] + h1 * Wd[(64 + lane) * 3 + 2]
             + p0 * Wd[(HID + lane) * 3 + 2] + p1 * Wd[(HID + 64 + lane) * 3 + 2];
#pragma unroll
    for (int o = 32; o > 0; o >>= 1) {
        a0 += __shfl_xor(a0, o);
        a1 += __shfl_xor(a1, o);
        a2 += __shfl_xor(a2, o);
    }
    if (lane == 0) {
        out[(size_t)node * 3 + 0] = a0 + bd[0];
        out[(size_t)node * 3 + 1] = a1 + bd[1];
        out[(size_t)node * 3 + 2] = a2 + bd[2];
    }
}

// ---------- launch ----------
static inline int cdiv(long long a, int b) { return (int)((a + b - 1) / b); }

extern "C" void kernel_launch(void* const* d_in, const int* in_sizes, int n_in,
                              void* d_out, int out_size, void* d_ws, size_t ws_size,
                              hipStream_t stream) {
    const float* x_r = (const float*)d_in[0];
    const float* x_c = (const float*)d_in[1];
    const int* ei_r = (const int*)d_in[2];
    const int* ei_c = (const int*)d_in[3];
    const float* W_r1 = (const float*)d_in[5];
    const float* as_r1 = (const float*)d_in[6];
    const float* ad_r1 = (const float*)d_in[7];
    const float* b_r1 = (const float*)d_in[8];
    const float* W_r2 = (const float*)d_in[9];
    const float* as_r2 = (const float*)d_in[10];
    const float* ad_r2 = (const float*)d_in[11];
    const float* b_r2 = (const float*)d_in[12];
    const float* W_c1 = (const float*)d_in[13];
    const float* as_c1 = (const float*)d_in[14];
    const float* ad_c1 = (const float*)d_in[15];
    const float* b_c1 = (const float*)d_in[16];
    const float* W_c2 = (const float*)d_in[17];
    const float* as_c2 = (const float*)d_in[18];
    const float* ad_c2 = (const float*)d_in[19];
    const float* b_c2 = (const float*)d_in[20];
    const float* W_dec = (const float*)d_in[21];
    const float* b_dec = (const float*)d_in[22];
    float* out = (float*)d_out;

    const int N_R = in_sizes[0] / 6;
    const int N_C = in_sizes[1] / 6;
    const int E_R = in_sizes[2] / 2;
    const int E_C = in_sizes[3] / 2;

    float* ws = (float*)d_ws;
    size_t off = 0;
    auto alloc = [&](size_t nf) {
        float* p = ws + off;
        off += (nf + 3) & ~(size_t)3;
        return p;
    };
    float* r_h    = alloc((size_t)N_R * HID);
    float* r_agg  = alloc((size_t)N_R * HID);
    float* c_h    = alloc((size_t)N_C * HID);
    float* c_agg  = alloc((size_t)N_C * HID);
    float* r_es = alloc(N_R);
    float* r_ed = alloc(N_R);
    float* c_es = alloc(N_C);
    float* c_ed = alloc(N_C);
    float* nr2 = alloc((size_t)N_R + 512);
    _Float16* hr2 = (_Float16*)alloc((size_t)N_R * HID / 2);
    _Float16* hc2 = (_Float16*)alloc((size_t)N_C * HID / 2);
    int* cand_i = (int*)alloc((size_t)N_C * NCAND);
    int* nn_idx = (int*)alloc((size_t)N_C * 3);
    // CSR (resting)
    int* r_deg = (int*)alloc(N_R);
    int* r_off = (int*)alloc((size_t)N_R + 1);
    int* r_cur = (int*)alloc(N_R);
    int* r_csr = (int*)alloc((size_t)E_R + N_R);
    int* r_bsum = (int*)alloc(256);
    // CSR (collider)
    int* c_deg = (int*)alloc(N_C);
    int* c_off = (int*)alloc((size_t)N_C + 1);
    int* c_cur = (int*)alloc(N_C);
    int* c_csr = (int*)alloc((size_t)E_C + N_C);
    int* c_bsum = (int*)alloc(256);
    // NN pooling CSR
    int* p_cnt = (int*)alloc(N_R);
    int* p_off = (int*)alloc((size_t)N_R + 1);
    int* p_cur = (int*)alloc(N_R);
    int* p_list = (int*)alloc((size_t)N_C * 3);
    int* p_bsum = (int*)alloc(256);
    (void)ws_size; (void)n_in; (void)out_size;

    auto build_csr = [&](const int* ei, int E, int n, int* deg, int* offp, int* cur,
                         int* csr, int* bsum) {
        hipMemsetAsync(deg, 0, (size_t)n * sizeof(int), stream);
        k_deg<<<cdiv(E + n, 256), 256, 0, stream>>>(ei, E, n, deg);
        int nb = cdiv(n, 256);
        k_chunksum<<<nb, 256, 0, stream>>>(deg, bsum, n);
        k_scan_small<<<1, 256, 0, stream>>>(bsum, nb);
        k_scan_apply<<<nb, 256, 0, stream>>>(deg, bsum, offp, cur, n);
        k_scatter<<<cdiv(E + n, 256), 256, 0, stream>>>(ei, E, n, cur, csr);
    };
    auto gat = [&](const float* x, int d_in_dim, int n, const int* offp, const int* csr,
                   const float* W, const float* as_, const float* ad_, const float* b,
                   float* h, float* es, float* ed, float* agg,
                   _Float16* h16, float* n2) {
        k_linear<<<cdiv(n, 4), 128, 0, stream>>>(x, W, as_, ad_, h, es, ed, d_in_dim, n);
        k_gat_csr<<<cdiv(n, 4), 256, 0, stream>>>(offp, csr, es, ed, h, b, agg, n, h16, n2);
    };

    // resting branch
    build_csr(ei_r, E_R, N_R, r_deg, r_off, r_cur, r_csr, r_bsum);
    gat(x_r, 6, N_R, r_off, r_csr, W_r1, as_r1, ad_r1, b_r1, r_h, r_es, r_ed, r_agg,
        nullptr, nullptr);
    gat(r_agg, HID, N_R, r_off, r_csr, W_r2, as_r2, ad_r2, b_r2, r_h, r_es, r_ed, r_agg,
        hr2, nr2);
    // collider branch
    build_csr(ei_c, E_C, N_C, c_deg, c_off, c_cur, c_csr, c_bsum);
    gat(x_c, 6, N_C, c_off, c_csr, W_c1, as_c1, ad_c1, b_c1, c_h, c_es, c_ed, c_agg,
        nullptr, nullptr);
    gat(c_agg, HID, N_C, c_off, c_csr, W_c2, as_c2, ad_c2, b_c2, c_h, c_es, c_ed, c_agg,
        hc2, nullptr);

    // MFMA candidate scan
    int RS = cdiv(N_R, CSPLIT * 64) * 64;
    dim3 sgrid(cdiv(N_C, KNN_CB), CSPLIT);
    k_knn_scan<<<sgrid, 256, 0, stream>>>(hr2, hc2, nr2, N_C, N_R, RS, cand_i);

    // exact rerank -> top-3 indices (no atomics)
    k_rerank<<<N_C, 256, 0, stream>>>(cand_i, c_agg, r_agg, nr2, N_R, nn_idx);

    // build pooling CSR: resting node -> colliders that picked it
    {
        int m = N_C * 3;
        hipMemsetAsync(p_cnt, 0, (size_t)N_R * sizeof(int), stream);
        k_nn_hist<<<cdiv(m, 256), 256, 0, stream>>>(nn_idx, m, N_R, p_cnt);
        int nb = cdiv(N_R, 256);
        k_chunksum<<<nb, 256, 0, stream>>>(p_cnt, p_bsum, N_R);
        k_scan_small<<<1, 256, 0, stream>>>(p_bsum, nb);
        k_scan_apply<<<nb, 256, 0, stream>>>(p_cnt, p_bsum, p_off, p_cur, N_R);
        k_nn_scatter<<<cdiv(m, 256), 256, 0, stream>>>(nn_idx, m, N_R, p_cur, p_list);
    }

    // fused pooled-mean + decode
    k_pool_decode<<<cdiv(N_R, 4), 256, 0, stream>>>(p_off, p_list, c_agg, r_agg,
                                                    W_dec, b_dec, out, N_R);
}

// Round 12
// 934.567 us; speedup vs baseline: 1.9113x; 1.9113x over previous
//
#include <hip/hip_runtime.h>
#include <hip/hip_bf16.h>

#define HID 128
#define NEG_SLOPE 0.2f
#define CSPLIT 8
#define KNN_CB 64
#define NCAND (CSPLIT * 12)   // 96 candidates per collider (3 per row-class per split)
#define POOL_LT 32            // rows longer than this go to the parallel long-row kernel

typedef _Float16 f16x8 __attribute__((ext_vector_type(8)));
typedef float f32x4 __attribute__((ext_vector_type(4)));

// ---------- helpers ----------
__device__ __forceinline__ bool cand_lt(float d1, int i1, float d2, int i2) {
    return d1 < d2 || (d1 == d2 && i1 < i2);
}
__device__ __forceinline__ void ins3(float s, int r, float fd[3], int fi[3]) {
    if (!cand_lt(s, r, fd[2], fi[2])) return;
    if (cand_lt(s, r, fd[0], fi[0])) {
        fd[2]=fd[1];fi[2]=fi[1]; fd[1]=fd[0];fi[1]=fi[0]; fd[0]=s;fi[0]=r;
    } else if (cand_lt(s, r, fd[1], fi[1])) {
        fd[2]=fd[1];fi[2]=fi[1]; fd[1]=s;fi[1]=r;
    } else {
        fd[2]=s;fi[2]=r;
    }
}

// ---------- CSR build (also reused for NN pooling lists) ----------
__global__ void k_deg(const int* __restrict__ ei, int E, int n, int* __restrict__ deg) {
    int i = blockIdx.x * blockDim.x + threadIdx.x;
    if (i >= E + n) return;
    int d = (i < E) ? ei[E + i] : i - E;
    atomicAdd(&deg[d], 1);
}

__global__ void k_chunksum(const int* __restrict__ deg, int* __restrict__ bsum, int n) {
    int t = threadIdx.x;
    int i = blockIdx.x * 256 + t;
    int v = (i < n) ? deg[i] : 0;
#pragma unroll
    for (int o = 1; o < 64; o <<= 1) v += __shfl_xor(v, o);
    __shared__ int wsum[4];
    if ((t & 63) == 0) wsum[t >> 6] = v;
    __syncthreads();
    if (t == 0) bsum[blockIdx.x] = wsum[0] + wsum[1] + wsum[2] + wsum[3];
}

__global__ void k_scan_small(int* __restrict__ a, int nb) {
    __shared__ int buf[256];
    int t = threadIdx.x;
    int v = (t < nb) ? a[t] : 0;
    buf[t] = v;
    __syncthreads();
    for (int o = 1; o < 256; o <<= 1) {
        int add = (t >= o) ? buf[t - o] : 0;
        __syncthreads();
        buf[t] += add;
        __syncthreads();
    }
    if (t < nb) a[t] = buf[t] - v;
    if (t == 0) a[nb] = buf[nb - 1];
}

__global__ void k_scan_apply(const int* __restrict__ deg, const int* __restrict__ bsum,
                             int* __restrict__ off, int* __restrict__ cur, int n) {
    __shared__ int buf[256];
    int b = blockIdx.x, t = threadIdx.x;
    int i = b * 256 + t;
    int v = (i < n) ? deg[i] : 0;
    buf[t] = v;
    __syncthreads();
    for (int o = 1; o < 256; o <<= 1) {
        int add = (t >= o) ? buf[t - o] : 0;
        __syncthreads();
        buf[t] += add;
        __syncthreads();
    }
    int excl = bsum[b] + buf[t] - v;
    if (i < n) { off[i] = excl; cur[i] = excl; }
    if (b == 0 && t == 0) off[n] = bsum[gridDim.x];
}

__global__ void k_scatter(const int* __restrict__ ei, int E, int n,
                          int* __restrict__ cursor, int* __restrict__ csr) {
    int i = blockIdx.x * blockDim.x + threadIdx.x;
    if (i >= E + n) return;
    int s, d;
    if (i < E) { s = ei[i]; d = ei[E + i]; } else { s = d = i - E; }
    int pos = atomicAdd(&cursor[d], 1);
    csr[pos] = s;
}

// ---------- NN-pool list build ----------
__global__ void k_nn_hist(const int* __restrict__ nn, int m, int n_r, int* __restrict__ cnt) {
    int i = blockIdx.x * blockDim.x + threadIdx.x;
    if (i >= m) return;
    int r = nn[i];
    if ((unsigned)r < (unsigned)n_r) atomicAdd(&cnt[r], 1);
}

__global__ void k_nn_scatter(const int* __restrict__ nn, int m, int n_r,
                             int* __restrict__ cur, int* __restrict__ plist) {
    int i = blockIdx.x * blockDim.x + threadIdx.x;
    if (i >= m) return;
    int r = nn[i];
    if ((unsigned)r < (unsigned)n_r) {
        int pos = atomicAdd(&cur[r], 1);
        plist[pos] = i / 3;          // collider index
    }
}

// flag rows longer than POOL_LT into a compacted list (device count)
__global__ void k_flag_long(const int* __restrict__ poff, int n,
                            int* __restrict__ lcnt, int* __restrict__ long_list) {
    int i = blockIdx.x * blockDim.x + threadIdx.x;
    if (i >= n) return;
    if (poff[i + 1] - poff[i] > POOL_LT) {
        int pos = atomicAdd(lcnt, 1);
        long_list[pos] = i;
    }
}

// one block per LONG row (grid-stride over device-side count): 4 waves stride
// the entry list, LDS combine, write mean into pooled[node].
__global__ __launch_bounds__(256) void k_pool_long(
    const int* __restrict__ lcnt, const int* __restrict__ long_list,
    const int* __restrict__ poff, const int* __restrict__ plist,
    const float* __restrict__ hc, float* __restrict__ pooled) {
    __shared__ float red[4][HID];
    int L = *lcnt;
    int t = threadIdx.x, w = t >> 6, lane = t & 63;
    for (int li = blockIdx.x; li < L; li += gridDim.x) {
        int node = long_list[li];
        int beg = poff[node], end = poff[node + 1];
        float p0a = 0.f, p1a = 0.f, p0b = 0.f, p1b = 0.f;
        int j = beg + w;
        for (; j + 4 < end; j += 8) {             // 2-way unroll (indep chains)
            int c0 = plist[j];
            int c1 = plist[j + 4];
            p0a += hc[(size_t)c0 * HID + lane];
            p1a += hc[(size_t)c0 * HID + 64 + lane];
            p0b += hc[(size_t)c1 * HID + lane];
            p1b += hc[(size_t)c1 * HID + 64 + lane];
        }
        if (j < end) {
            int c0 = plist[j];
            p0a += hc[(size_t)c0 * HID + lane];
            p1a += hc[(size_t)c0 * HID + 64 + lane];
        }
        red[w][lane] = p0a + p0b;
        red[w][64 + lane] = p1a + p1b;
        __syncthreads();
        if (w == 0) {
            float s0 = red[0][lane] + red[1][lane] + red[2][lane] + red[3][lane];
            float s1 = red[0][64 + lane] + red[1][64 + lane] + red[2][64 + lane] + red[3][64 + lane];
            float inv = 1.f / (float)(end - beg);
            pooled[(size_t)node * HID + lane] = s0 * inv;
            pooled[(size_t)node * HID + 64 + lane] = s1 * inv;
        }
        __syncthreads();
    }
}

// ---------- linear: 4 nodes per block (128 thr), W reads shared ----------
__global__ __launch_bounds__(128) void k_linear(
    const float* __restrict__ x, const float* __restrict__ W,
    const float* __restrict__ a_src, const float* __restrict__ a_dst,
    float* __restrict__ h, float* __restrict__ es, float* __restrict__ ed,
    int d_in, int n) {
    int n0 = blockIdx.x * 4;
    int t = threadIdx.x;
    int w = t >> 6, lane = t & 63;
    __shared__ float xs[4][HID];
    __shared__ float p1[2], p2[2];
#pragma unroll
    for (int u = 0; u < 4; ++u) {
        int node = n0 + u;
        if (t < d_in) xs[u][t] = (node < n) ? x[(size_t)node * d_in + t] : 0.f;
    }
    __syncthreads();
    float acc[4] = {0.f, 0.f, 0.f, 0.f};
    for (int k = 0; k < d_in; ++k) {
        float wv = W[k * HID + t];
#pragma unroll
        for (int u = 0; u < 4; ++u) acc[u] += xs[u][k] * wv;
    }
    float asv = a_src[t], adv = a_dst[t];
    for (int u = 0; u < 4; ++u) {
        int node = n0 + u;
        if (node >= n) break;                     // uniform across block
        h[(size_t)node * HID + t] = acc[u];
        float v1 = acc[u] * asv, v2 = acc[u] * adv;
#pragma unroll
        for (int o = 32; o > 0; o >>= 1) { v1 += __shfl_xor(v1, o); v2 += __shfl_xor(v2, o); }
        if (lane == 0) { p1[w] = v1; p2[w] = v2; }
        __syncthreads();
        if (t == 0) { es[node] = p1[0] + p1[1]; ed[node] = p2[0] + p2[1]; }
        __syncthreads();
    }
}

// ---------- fused GAT aggregation over CSR (wave per dst node) ----------
__global__ __launch_bounds__(256) void k_gat_csr(
    const int* __restrict__ off, const int* __restrict__ csr,
    const float* __restrict__ es, const float* __restrict__ ed,
    const float* __restrict__ h, const float* __restrict__ b,
    float* __restrict__ agg, int n,
    _Float16* __restrict__ h16, float* __restrict__ n2) {
    int node = blockIdx.x * 4 + (threadIdx.x >> 6);
    int lane = threadIdx.x & 63;
    if (node >= n) return;                        // wave-uniform
    int beg = off[node], end = off[node + 1];
    float edd = ed[node];
    float m = -INFINITY;
    for (int j = beg + lane; j < end; j += 64) {
        int s = csr[j];
        float e = es[s] + edd;
        e = e > 0.f ? e : NEG_SLOPE * e;
        m = fmaxf(m, e);
    }
#pragma unroll
    for (int o = 32; o > 0; o >>= 1) m = fmaxf(m, __shfl_xor(m, o));
    float den = 0.f, a0 = 0.f, a1 = 0.f;
    int j = beg;
    for (; j + 1 < end; j += 2) {
        int s0 = csr[j], s1 = csr[j + 1];
        float e0 = es[s0] + edd;
        float e1 = es[s1] + edd;
        e0 = e0 > 0.f ? e0 : NEG_SLOPE * e0;
        e1 = e1 > 0.f ? e1 : NEG_SLOPE * e1;
        float ex0 = expf(e0 - m);
        float ex1 = expf(e1 - m);
        float h00 = h[(size_t)s0 * HID + lane];
        float h01 = h[(size_t)s0 * HID + 64 + lane];
        float h10 = h[(size_t)s1 * HID + lane];
        float h11 = h[(size_t)s1 * HID + 64 + lane];
        den += ex0 + ex1;
        a0 += ex0 * h00 + ex1 * h10;
        a1 += ex0 * h01 + ex1 * h11;
    }
    if (j < end) {
        int s0 = csr[j];
        float e0 = es[s0] + edd;
        e0 = e0 > 0.f ? e0 : NEG_SLOPE * e0;
        float ex0 = expf(e0 - m);
        den += ex0;
        a0 += ex0 * h[(size_t)s0 * HID + lane];
        a1 += ex0 * h[(size_t)s0 * HID + 64 + lane];
    }
    float inv = 1.f / fmaxf(den, 1e-16f);
    float v0 = a0 * inv + b[lane];
    float v1 = a1 * inv + b[64 + lane];
    float r0 = v0 > 0.f ? v0 : 0.f;
    float r1 = v1 > 0.f ? v1 : 0.f;
    agg[(size_t)node * HID + lane] = r0;
    agg[(size_t)node * HID + 64 + lane] = r1;
    if (h16) {
        h16[(size_t)node * HID + lane] = (_Float16)r0;
        h16[(size_t)node * HID + 64 + lane] = (_Float16)r1;
    }
    if (n2) {
        float s2 = r0 * r0 + r1 * r1;
#pragma unroll
        for (int o = 32; o > 0; o >>= 1) s2 += __shfl_xor(s2, o);
        if (lane == 0) n2[node] = s2;
    }
}

// ---------- MFMA KNN scan ----------
__global__ __launch_bounds__(256) void k_knn_scan(
    const _Float16* __restrict__ hr2, const _Float16* __restrict__ hc2,
    const float* __restrict__ nr2, int n_c, int n_r, int rs_chunk,
    int* __restrict__ cand_i) {
    __shared__ _Float16 lds[2][64 * HID];
    int t = threadIdx.x, w = t >> 6, lane = t & 63;
    int li = lane & 15, q = lane >> 4;
    int c0 = blockIdx.x * KNN_CB;
    int split = blockIdx.y;
    int rbeg = split * rs_chunk;
    int rows = min(rs_chunk, n_r - rbeg);
    int rend = rbeg + rows;

    if (rows <= 0) {
        int c = c0 + w * 16 + li;
        if (c < n_c) {
            size_t base = ((size_t)(c * CSPLIT + split) * 4 + q) * 3;
            for (int k = 0; k < 3; ++k) cand_i[base + k] = 0x7fffffff;
        }
        return;
    }

    // B fragments: collider col = li, k = ks*32 + q*8 .. +7
    f16x8 bf[4];
    {
        int c = c0 + w * 16 + li;
        int cc = min(c, n_c - 1);
#pragma unroll
        for (int ks = 0; ks < 4; ++ks)
            bf[ks] = *(const f16x8*)(hc2 + (size_t)cc * HID + ks * 32 + q * 8);
    }

    float bd[3]; int bi[3];
#pragma unroll
    for (int k = 0; k < 3; ++k) { bd[k] = INFINITY; bi[k] = 0x7fffffff; }

    int nch = (rows + 63) >> 6;

    auto STAGE = [&](int bsel, int R) {
#pragma unroll
        for (int j = 0; j < 4; ++j) {
            int row = w * 16 + j * 4 + q;
            int gr = min(R + row, n_r - 1);
            int sslot = li ^ (row & 7);
            const _Float16* src = hr2 + (size_t)gr * HID + sslot * 8;
            _Float16* dst = &lds[bsel][(w * 16 + j * 4) * HID];  // wave-uniform
            __builtin_amdgcn_global_load_lds(
                (const __attribute__((address_space(1))) void*)src,
                (__attribute__((address_space(3))) void*)dst, 16, 0, 0);
        }
    };

    STAGE(0, rbeg);
    __syncthreads();

    for (int ch = 0; ch < nch; ++ch) {
        int cur = ch & 1;
        if (ch + 1 < nch) STAGE(cur ^ 1, rbeg + (ch + 1) * 64);  // prefetch
        int R = rbeg + ch * 64;
        const _Float16* buf = lds[cur];
        if (R + 64 <= rend) {
            float4 nrv[4];
#pragma unroll
            for (int tt = 0; tt < 4; ++tt)
                nrv[tt] = *(const float4*)(nr2 + R + tt * 16 + q * 4);
#pragma unroll
            for (int tt = 0; tt < 4; ++tt) {
                f32x4 a0 = {0.f, 0.f, 0.f, 0.f};
                int lr = tt * 16 + li;
                int swr = lr & 7;
#pragma unroll
                for (int ks = 0; ks < 4; ++ks) {
                    f16x8 af = *(const f16x8*)(&buf[lr * HID + (((ks * 4 + q) ^ swr) << 3)]);
                    a0 = __builtin_amdgcn_mfma_f32_16x16x32_f16(af, bf[ks], a0, 0, 0, 0);
                }
                int r_base = R + tt * 16 + q * 4;
                float sv[4] = {nrv[tt].x, nrv[tt].y, nrv[tt].z, nrv[tt].w};
#pragma unroll
                for (int i = 0; i < 4; ++i)
                    ins3(sv[i] - 2.f * a0[i], r_base + i, bd, bi);
            }
        } else {
            int rows_rem = rend - R;
#pragma unroll
            for (int tt = 0; tt < 4; ++tt) {
                int br = tt * 16;
                if (br < rows_rem) {
                    f32x4 a0 = {0.f, 0.f, 0.f, 0.f};
                    int lr = br + li;
                    int swr = lr & 7;
#pragma unroll
                    for (int ks = 0; ks < 4; ++ks) {
                        f16x8 af = *(const f16x8*)(&buf[lr * HID + (((ks * 4 + q) ^ swr) << 3)]);
                        a0 = __builtin_amdgcn_mfma_f32_16x16x32_f16(af, bf[ks], a0, 0, 0, 0);
                    }
                    int r_base = R + br + q * 4;
                    float4 nrv = *(const float4*)(nr2 + r_base);
                    float sv[4] = {nrv.x, nrv.y, nrv.z, nrv.w};
#pragma unroll
                    for (int i = 0; i < 4; ++i) {
                        int r = r_base + i;
                        if (r < rend) ins3(sv[i] - 2.f * a0[i], r, bd, bi);
                    }
                }
            }
        }
        __syncthreads();
    }

    {
        int c = c0 + w * 16 + li;
        if (c < n_c) {
            size_t base = ((size_t)(c * CSPLIT + split) * 4 + q) * 3;
#pragma unroll
            for (int k = 0; k < 3; ++k) cand_i[base + k] = bi[k];
        }
    }
}

// ---------- exact rerank: block per collider -> top-3 indices (NO atomics) ---
__global__ __launch_bounds__(256, 4) void k_rerank(
    const int* __restrict__ cand_i, const float* __restrict__ hc,
    const float* __restrict__ hr, const float* __restrict__ nr2,
    int n_r, int* __restrict__ nn_idx) {
    int c = blockIdx.x;
    int t = threadIdx.x;
    __shared__ float hcs[HID];
    __shared__ int ci[NCAND];
    __shared__ float sc[NCAND];
    __shared__ int scr[NCAND];
    if (t < HID) hcs[t] = hc[(size_t)c * HID + t];
    if (t < NCAND) {
        int r = cand_i[(size_t)c * NCAND + t];
        ci[t] = ((unsigned)r < (unsigned)n_r) ? r : -1;
    }
    __syncthreads();

    int k4 = t & 31;
    int g = t >> 5;                                // 0..7
    const float4* hr4 = (const float4*)hr;
    float4 a = ((const float4*)hcs)[k4];

    int rj[12];
    float4 v[12];
#pragma unroll
    for (int p = 0; p < 12; ++p) {                 // issue all loads (MLP)
        rj[p] = ci[p * 8 + g];
        v[p] = hr4[(size_t)max(rj[p], 0) * 32 + k4];
    }
    float fd[3] = {INFINITY, INFINITY, INFINITY};
    int fi[3] = {0x7fffffff, 0x7fffffff, 0x7fffffff};
#pragma unroll
    for (int p = 0; p < 12; ++p) {
        float d = a.x * v[p].x + a.y * v[p].y + a.z * v[p].z + a.w * v[p].w;
#pragma unroll
        for (int o = 1; o < 32; o <<= 1) d += __shfl_xor(d, o);
        if (k4 == 0) {
            int j = p * 8 + g;
            sc[j] = (rj[p] >= 0) ? nr2[rj[p]] - 2.f * d : INFINITY;
            scr[j] = (rj[p] >= 0) ? rj[p] : 0x7fffffff;
        }
    }
    __syncthreads();
    if (t < 64) {
        ins3(sc[t], scr[t], fd, fi);
        if (t < 32) ins3(sc[64 + t], scr[64 + t], fd, fi);
#pragma unroll
        for (int o = 1; o < 64; o <<= 1) {
            float sd0 = __shfl_xor(fd[0], o), sd1 = __shfl_xor(fd[1], o), sd2 = __shfl_xor(fd[2], o);
            int si0 = __shfl_xor(fi[0], o), si1 = __shfl_xor(fi[1], o), si2 = __shfl_xor(fi[2], o);
            ins3(sd0, si0, fd, fi);
            ins3(sd1, si1, fd, fi);
            ins3(sd2, si2, fd, fi);
        }
        if (t == 0) {
            nn_idx[c * 3 + 0] = fi[0];
            nn_idx[c * 3 + 1] = fi[1];
            nn_idx[c * 3 + 2] = fi[2];
        }
    }
}

// ---------- fused pooled-mean + decode (wave per resting node) ----------
// short rows (<= POOL_LT): serial gather; long rows: read precomputed mean.
__global__ __launch_bounds__(256) void k_pool_decode(
    const int* __restrict__ poff, const int* __restrict__ plist,
    const float* __restrict__ pooled_long,
    const float* __restrict__ hc, const float* __restrict__ hr,
    const float* __restrict__ Wd, const float* __restrict__ bd,
    float* __restrict__ out, int n) {
    int node = blockIdx.x * 4 + (threadIdx.x >> 6);
    int lane = threadIdx.x & 63;
    if (node >= n) return;                        // wave-uniform
    int beg = poff[node], end = poff[node + 1];
    int len = end - beg;
    float p0, p1;
    if (len > POOL_LT) {
        p0 = pooled_long[(size_t)node * HID + lane];
        p1 = pooled_long[(size_t)node * HID + 64 + lane];
    } else {
        p0 = 0.f;
        p1 = 0.f;
        for (int j = beg; j < end; ++j) {
            int c = plist[j];
            p0 += hc[(size_t)c * HID + lane];
            p1 += hc[(size_t)c * HID + 64 + lane];
        }
        float inv = 1.f / fmaxf((float)len, 1.f);
        p0 *= inv;
        p1 *= inv;
    }
    float h0 = hr[(size_t)node * HID + lane];
    float h1 = hr[(size_t)node * HID + 64 + lane];
    float a0 = h0 * Wd[lane * 3 + 0] + h1 * Wd[(64 + lane) * 3 + 0]
             + p0 * Wd[(HID + lane) * 3 + 0] + p1 * Wd[(HID + 64 + lane) * 3 + 0];
    float a1 = h0 * Wd[lane * 3 + 1] + h1 * Wd[(64 + lane) * 3 + 1]
             + p0 * Wd[(HID + lane) * 3 + 1] + p1 * Wd[(HID + 64 + lane) * 3 + 1];
    float a2 = h0 * Wd[lane * 3 + 2] + h1 * Wd[(64 + lane) * 3 + 2]
             + p0 * Wd[(HID + lane) * 3 + 2] + p1 * Wd[(HID + 64 + lane) * 3 + 2];
#pragma unroll
    for (int o = 32; o > 0; o >>= 1) {
        a0 += __shfl_xor(a0, o);
        a1 += __shfl_xor(a1, o);
        a2 += __shfl_xor(a2, o);
    }
    if (lane == 0) {
        out[(size_t)node * 3 + 0] = a0 + bd[0];
        out[(size_t)node * 3 + 1] = a1 + bd[1];
        out[(size_t)node * 3 + 2] = a2 + bd[2];
    }
}

// ---------- launch ----------
static inline int cdiv(long long a, int b) { return (int)((a + b - 1) / b); }

extern "C" void kernel_launch(void* const* d_in, const int* in_sizes, int n_in,
                              void* d_out, int out_size, void* d_ws, size_t ws_size,
                              hipStream_t stream) {
    const float* x_r = (const float*)d_in[0];
    const float* x_c = (const float*)d_in[1];
    const int* ei_r = (const int*)d_in[2];
    const int* ei_c = (const int*)d_in[3];
    const float* W_r1 = (const float*)d_in[5];
    const float* as_r1 = (const float*)d_in[6];
    const float* ad_r1 = (const float*)d_in[7];
    const float* b_r1 = (const float*)d_in[8];
    const float* W_r2 = (const float*)d_in[9];
    const float* as_r2 = (const float*)d_in[10];
    const float* ad_r2 = (const float*)d_in[11];
    const float* b_r2 = (const float*)d_in[12];
    const float* W_c1 = (const float*)d_in[13];
    const float* as_c1 = (const float*)d_in[14];
    const float* ad_c1 = (const float*)d_in[15];
    const float* b_c1 = (const float*)d_in[16];
    const float* W_c2 = (const float*)d_in[17];
    const float* as_c2 = (const float*)d_in[18];
    const float* ad_c2 = (const float*)d_in[19];
    const float* b_c2 = (const float*)d_in[20];
    const float* W_dec = (const float*)d_in[21];
    const float* b_dec = (const float*)d_in[22];
    float* out = (float*)d_out;

    const int N_R = in_sizes[0] / 6;
    const int N_C = in_sizes[1] / 6;
    const int E_R = in_sizes[2] / 2;
    const int E_C = in_sizes[3] / 2;

    float* ws = (float*)d_ws;
    size_t off = 0;
    auto alloc = [&](size_t nf) {
        float* p = ws + off;
        off += (nf + 3) & ~(size_t)3;
        return p;
    };
    float* r_h    = alloc((size_t)N_R * HID);
    float* r_agg  = alloc((size_t)N_R * HID);
    float* c_h    = alloc((size_t)N_C * HID);
    float* c_agg  = alloc((size_t)N_C * HID);
    float* pooled = alloc((size_t)N_R * HID);   // only long rows written/read
    float* r_es = alloc(N_R);
    float* r_ed = alloc(N_R);
    float* c_es = alloc(N_C);
    float* c_ed = alloc(N_C);
    float* nr2 = alloc((size_t)N_R + 512);
    _Float16* hr2 = (_Float16*)alloc((size_t)N_R * HID / 2);
    _Float16* hc2 = (_Float16*)alloc((size_t)N_C * HID / 2);
    int* cand_i = (int*)alloc((size_t)N_C * NCAND);
    int* nn_idx = (int*)alloc((size_t)N_C * 3);
    // CSR (resting)
    int* r_deg = (int*)alloc(N_R);
    int* r_off = (int*)alloc((size_t)N_R + 1);
    int* r_cur = (int*)alloc(N_R);
    int* r_csr = (int*)alloc((size_t)E_R + N_R);
    int* r_bsum = (int*)alloc(256);
    // CSR (collider)
    int* c_deg = (int*)alloc(N_C);
    int* c_off = (int*)alloc((size_t)N_C + 1);
    int* c_cur = (int*)alloc(N_C);
    int* c_csr = (int*)alloc((size_t)E_C + N_C);
    int* c_bsum = (int*)alloc(256);
    // NN pooling CSR + long-row list
    int* p_cnt = (int*)alloc(N_R);
    int* p_off = (int*)alloc((size_t)N_R + 1);
    int* p_cur = (int*)alloc(N_R);
    int* p_list = (int*)alloc((size_t)N_C * 3);
    int* p_bsum = (int*)alloc(256);
    int* l_cnt = (int*)alloc(4);
    int* l_list = (int*)alloc(N_R);
    (void)ws_size; (void)n_in; (void)out_size;

    auto build_csr = [&](const int* ei, int E, int n, int* deg, int* offp, int* cur,
                         int* csr, int* bsum) {
        hipMemsetAsync(deg, 0, (size_t)n * sizeof(int), stream);
        k_deg<<<cdiv(E + n, 256), 256, 0, stream>>>(ei, E, n, deg);
        int nb = cdiv(n, 256);
        k_chunksum<<<nb, 256, 0, stream>>>(deg, bsum, n);
        k_scan_small<<<1, 256, 0, stream>>>(bsum, nb);
        k_scan_apply<<<nb, 256, 0, stream>>>(deg, bsum, offp, cur, n);
        k_scatter<<<cdiv(E + n, 256), 256, 0, stream>>>(ei, E, n, cur, csr);
    };
    auto gat = [&](const float* x, int d_in_dim, int n, const int* offp, const int* csr,
                   const float* W, const float* as_, const float* ad_, const float* b,
                   float* h, float* es, float* ed, float* agg,
                   _Float16* h16, float* n2) {
        k_linear<<<cdiv(n, 4), 128, 0, stream>>>(x, W, as_, ad_, h, es, ed, d_in_dim, n);
        k_gat_csr<<<cdiv(n, 4), 256, 0, stream>>>(offp, csr, es, ed, h, b, agg, n, h16, n2);
    };

    // resting branch
    build_csr(ei_r, E_R, N_R, r_deg, r_off, r_cur, r_csr, r_bsum);
    gat(x_r, 6, N_R, r_off, r_csr, W_r1, as_r1, ad_r1, b_r1, r_h, r_es, r_ed, r_agg,
        nullptr, nullptr);
    gat(r_agg, HID, N_R, r_off, r_csr, W_r2, as_r2, ad_r2, b_r2, r_h, r_es, r_ed, r_agg,
        hr2, nr2);
    // collider branch
    build_csr(ei_c, E_C, N_C, c_deg, c_off, c_cur, c_csr, c_bsum);
    gat(x_c, 6, N_C, c_off, c_csr, W_c1, as_c1, ad_c1, b_c1, c_h, c_es, c_ed, c_agg,
        nullptr, nullptr);
    gat(c_agg, HID, N_C, c_off, c_csr, W_c2, as_c2, ad_c2, b_c2, c_h, c_es, c_ed, c_agg,
        hc2, nullptr);

    // MFMA candidate scan
    int RS = cdiv(N_R, CSPLIT * 64) * 64;
    dim3 sgrid(cdiv(N_C, KNN_CB), CSPLIT);
    k_knn_scan<<<sgrid, 256, 0, stream>>>(hr2, hc2, nr2, N_C, N_R, RS, cand_i);

    // exact rerank -> top-3 indices (no atomics)
    k_rerank<<<N_C, 256, 0, stream>>>(cand_i, c_agg, r_agg, nr2, N_R, nn_idx);

    // build pooling CSR: resting node -> colliders that picked it
    {
        int m = N_C * 3;
        hipMemsetAsync(p_cnt, 0, (size_t)N_R * sizeof(int), stream);
        k_nn_hist<<<cdiv(m, 256), 256, 0, stream>>>(nn_idx, m, N_R, p_cnt);
        int nb = cdiv(N_R, 256);
        k_chunksum<<<nb, 256, 0, stream>>>(p_cnt, p_bsum, N_R);
        k_scan_small<<<1, 256, 0, stream>>>(p_bsum, nb);
        k_scan_apply<<<nb, 256, 0, stream>>>(p_cnt, p_bsum, p_off, p_cur, N_R);
        k_nn_scatter<<<cdiv(m, 256), 256, 0, stream>>>(nn_idx, m, N_R, p_cur, p_list);
        // long-row handling (hub skew): compact list + parallel mean
        hipMemsetAsync(l_cnt, 0, sizeof(int), stream);
        k_flag_long<<<cdiv(N_R, 256), 256, 0, stream>>>(p_off, N_R, l_cnt, l_list);
        k_pool_long<<<256, 256, 0, stream>>>(l_cnt, l_list, p_off, p_list, c_agg, pooled);
    }

    // fused pooled-mean + decode
    k_pool_decode<<<cdiv(N_R, 4), 256, 0, stream>>>(p_off, p_list, pooled, c_agg, r_agg,
                                                    W_dec, b_dec, out, N_R);
}

// Round 13
// 612.182 us; speedup vs baseline: 2.9179x; 1.5266x over previous
//
#include <hip/hip_runtime.h>
#include <hip/hip_bf16.h>

#define HID 128
#define NEG_SLOPE 0.2f
#define CSPLIT 8
#define KNN_CB 64
#define NCAND (CSPLIT * 12)   // 96 candidates per collider (3 per row-class per split)
#define SEG 64                // pooling segment size (caps serial chain & contention)

typedef _Float16 f16x8 __attribute__((ext_vector_type(8)));
typedef float f32x4 __attribute__((ext_vector_type(4)));

// ---------- helpers ----------
__device__ __forceinline__ bool cand_lt(float d1, int i1, float d2, int i2) {
    return d1 < d2 || (d1 == d2 && i1 < i2);
}
__device__ __forceinline__ void ins3(float s, int r, float fd[3], int fi[3]) {
    if (!cand_lt(s, r, fd[2], fi[2])) return;
    if (cand_lt(s, r, fd[0], fi[0])) {
        fd[2]=fd[1];fi[2]=fi[1]; fd[1]=fd[0];fi[1]=fi[0]; fd[0]=s;fi[0]=r;
    } else if (cand_lt(s, r, fd[1], fi[1])) {
        fd[2]=fd[1];fi[2]=fi[1]; fd[1]=s;fi[1]=r;
    } else {
        fd[2]=s;fi[2]=r;
    }
}

// ---------- CSR build (also reused for NN pooling lists) ----------
__global__ void k_deg(const int* __restrict__ ei, int E, int n, int* __restrict__ deg) {
    int i = blockIdx.x * blockDim.x + threadIdx.x;
    if (i >= E + n) return;
    int d = (i < E) ? ei[E + i] : i - E;
    atomicAdd(&deg[d], 1);
}

__global__ void k_chunksum(const int* __restrict__ deg, int* __restrict__ bsum, int n) {
    int t = threadIdx.x;
    int i = blockIdx.x * 256 + t;
    int v = (i < n) ? deg[i] : 0;
#pragma unroll
    for (int o = 1; o < 64; o <<= 1) v += __shfl_xor(v, o);
    __shared__ int wsum[4];
    if ((t & 63) == 0) wsum[t >> 6] = v;
    __syncthreads();
    if (t == 0) bsum[blockIdx.x] = wsum[0] + wsum[1] + wsum[2] + wsum[3];
}

__global__ void k_scan_small(int* __restrict__ a, int nb) {
    __shared__ int buf[256];
    int t = threadIdx.x;
    int v = (t < nb) ? a[t] : 0;
    buf[t] = v;
    __syncthreads();
    for (int o = 1; o < 256; o <<= 1) {
        int add = (t >= o) ? buf[t - o] : 0;
        __syncthreads();
        buf[t] += add;
        __syncthreads();
    }
    if (t < nb) a[t] = buf[t] - v;
    if (t == 0) a[nb] = buf[nb - 1];
}

__global__ void k_scan_apply(const int* __restrict__ deg, const int* __restrict__ bsum,
                             int* __restrict__ off, int* __restrict__ cur, int n) {
    __shared__ int buf[256];
    int b = blockIdx.x, t = threadIdx.x;
    int i = b * 256 + t;
    int v = (i < n) ? deg[i] : 0;
    buf[t] = v;
    __syncthreads();
    for (int o = 1; o < 256; o <<= 1) {
        int add = (t >= o) ? buf[t - o] : 0;
        __syncthreads();
        buf[t] += add;
        __syncthreads();
    }
    int excl = bsum[b] + buf[t] - v;
    if (i < n) { off[i] = excl; cur[i] = excl; }
    if (b == 0 && t == 0) off[n] = bsum[gridDim.x];
}

__global__ void k_scatter(const int* __restrict__ ei, int E, int n,
                          int* __restrict__ cursor, int* __restrict__ csr) {
    int i = blockIdx.x * blockDim.x + threadIdx.x;
    if (i >= E + n) return;
    int s, d;
    if (i < E) { s = ei[i]; d = ei[E + i]; } else { s = d = i - E; }
    int pos = atomicAdd(&cursor[d], 1);
    csr[pos] = s;
}

// ---------- NN-pool list build ----------
__global__ void k_nn_hist(const int* __restrict__ nn, int m, int n_r, int* __restrict__ cnt) {
    int i = blockIdx.x * blockDim.x + threadIdx.x;
    if (i >= m) return;
    int r = nn[i];
    if ((unsigned)r < (unsigned)n_r) atomicAdd(&cnt[r], 1);
}

__global__ void k_nn_scatter(const int* __restrict__ nn, int m, int n_r,
                             int* __restrict__ cur, int* __restrict__ plist) {
    int i = blockIdx.x * blockDim.x + threadIdx.x;
    if (i >= m) return;
    int r = nn[i];
    if ((unsigned)r < (unsigned)n_r) {
        int pos = atomicAdd(&cur[r], 1);
        plist[pos] = i / 3;          // collider index
    }
}

// split every nonzero pool row into SEG-entry segments (device-side count)
__global__ void k_build_segs(const int* __restrict__ poff, int n,
                             int* __restrict__ seg_cnt,
                             int* __restrict__ seg_node, int* __restrict__ seg_off) {
    int i = blockIdx.x * blockDim.x + threadIdx.x;
    if (i >= n) return;
    int beg = poff[i], end = poff[i + 1];
    int len = end - beg;
    if (len <= 0) return;
    int nseg = (len + SEG - 1) / SEG;
    int pos = atomicAdd(seg_cnt, nseg);
    for (int s = 0; s < nseg; ++s) {
        seg_node[pos + s] = i;
        seg_off[pos + s] = beg + s * SEG;
    }
}

// one block per segment (grid-stride over device count): 4 waves x 16 entries,
// LDS combine, ONE atomicAdd per lane-dim per segment.
__global__ __launch_bounds__(256) void k_pool_seg(
    const int* __restrict__ seg_cnt, const int* __restrict__ seg_node,
    const int* __restrict__ seg_off, const int* __restrict__ poff,
    const int* __restrict__ plist, const float* __restrict__ hc,
    float* __restrict__ pooled) {
    __shared__ float red[4][HID];
    int S = *seg_cnt;
    int t = threadIdx.x, w = t >> 6, lane = t & 63;
    for (int si = blockIdx.x; si < S; si += gridDim.x) {
        int node = seg_node[si];
        int beg = seg_off[si];
        int end = min(beg + SEG, poff[node + 1]);
        float p0 = 0.f, p1 = 0.f;
        for (int j = beg + w; j < end; j += 4) {
            int c = plist[j];
            p0 += hc[(size_t)c * HID + lane];
            p1 += hc[(size_t)c * HID + 64 + lane];
        }
        red[w][lane] = p0;
        red[w][64 + lane] = p1;
        __syncthreads();
        if (w == 0) {
            float s0 = red[0][lane] + red[1][lane] + red[2][lane] + red[3][lane];
            float s1 = red[0][64 + lane] + red[1][64 + lane]
                     + red[2][64 + lane] + red[3][64 + lane];
            atomicAdd(&pooled[(size_t)node * HID + lane], s0);
            atomicAdd(&pooled[(size_t)node * HID + 64 + lane], s1);
        }
        __syncthreads();
    }
}

// ---------- linear: 4 nodes per block (128 thr), W reads shared ----------
__global__ __launch_bounds__(128) void k_linear(
    const float* __restrict__ x, const float* __restrict__ W,
    const float* __restrict__ a_src, const float* __restrict__ a_dst,
    float* __restrict__ h, float* __restrict__ es, float* __restrict__ ed,
    int d_in, int n) {
    int n0 = blockIdx.x * 4;
    int t = threadIdx.x;
    int w = t >> 6, lane = t & 63;
    __shared__ float xs[4][HID];
    __shared__ float p1[2], p2[2];
#pragma unroll
    for (int u = 0; u < 4; ++u) {
        int node = n0 + u;
        if (t < d_in) xs[u][t] = (node < n) ? x[(size_t)node * d_in + t] : 0.f;
    }
    __syncthreads();
    float acc[4] = {0.f, 0.f, 0.f, 0.f};
    for (int k = 0; k < d_in; ++k) {
        float wv = W[k * HID + t];
#pragma unroll
        for (int u = 0; u < 4; ++u) acc[u] += xs[u][k] * wv;
    }
    float asv = a_src[t], adv = a_dst[t];
    for (int u = 0; u < 4; ++u) {
        int node = n0 + u;
        if (node >= n) break;                     // uniform across block
        h[(size_t)node * HID + t] = acc[u];
        float v1 = acc[u] * asv, v2 = acc[u] * adv;
#pragma unroll
        for (int o = 32; o > 0; o >>= 1) { v1 += __shfl_xor(v1, o); v2 += __shfl_xor(v2, o); }
        if (lane == 0) { p1[w] = v1; p2[w] = v2; }
        __syncthreads();
        if (t == 0) { es[node] = p1[0] + p1[1]; ed[node] = p2[0] + p2[1]; }
        __syncthreads();
    }
}

// ---------- fused GAT aggregation over CSR (wave per dst node) ----------
__global__ __launch_bounds__(256) void k_gat_csr(
    const int* __restrict__ off, const int* __restrict__ csr,
    const float* __restrict__ es, const float* __restrict__ ed,
    const float* __restrict__ h, const float* __restrict__ b,
    float* __restrict__ agg, int n,
    _Float16* __restrict__ h16, float* __restrict__ n2) {
    int node = blockIdx.x * 4 + (threadIdx.x >> 6);
    int lane = threadIdx.x & 63;
    if (node >= n) return;                        // wave-uniform
    int beg = off[node], end = off[node + 1];
    float edd = ed[node];
    float m = -INFINITY;
    for (int j = beg + lane; j < end; j += 64) {
        int s = csr[j];
        float e = es[s] + edd;
        e = e > 0.f ? e : NEG_SLOPE * e;
        m = fmaxf(m, e);
    }
#pragma unroll
    for (int o = 32; o > 0; o >>= 1) m = fmaxf(m, __shfl_xor(m, o));
    float den = 0.f, a0 = 0.f, a1 = 0.f;
    int j = beg;
    for (; j + 1 < end; j += 2) {
        int s0 = csr[j], s1 = csr[j + 1];
        float e0 = es[s0] + edd;
        float e1 = es[s1] + edd;
        e0 = e0 > 0.f ? e0 : NEG_SLOPE * e0;
        e1 = e1 > 0.f ? e1 : NEG_SLOPE * e1;
        float ex0 = expf(e0 - m);
        float ex1 = expf(e1 - m);
        float h00 = h[(size_t)s0 * HID + lane];
        float h01 = h[(size_t)s0 * HID + 64 + lane];
        float h10 = h[(size_t)s1 * HID + lane];
        float h11 = h[(size_t)s1 * HID + 64 + lane];
        den += ex0 + ex1;
        a0 += ex0 * h00 + ex1 * h10;
        a1 += ex0 * h01 + ex1 * h11;
    }
    if (j < end) {
        int s0 = csr[j];
        float e0 = es[s0] + edd;
        e0 = e0 > 0.f ? e0 : NEG_SLOPE * e0;
        float ex0 = expf(e0 - m);
        den += ex0;
        a0 += ex0 * h[(size_t)s0 * HID + lane];
        a1 += ex0 * h[(size_t)s0 * HID + 64 + lane];
    }
    float inv = 1.f / fmaxf(den, 1e-16f);
    float v0 = a0 * inv + b[lane];
    float v1 = a1 * inv + b[64 + lane];
    float r0 = v0 > 0.f ? v0 : 0.f;
    float r1 = v1 > 0.f ? v1 : 0.f;
    agg[(size_t)node * HID + lane] = r0;
    agg[(size_t)node * HID + 64 + lane] = r1;
    if (h16) {
        h16[(size_t)node * HID + lane] = (_Float16)r0;
        h16[(size_t)node * HID + 64 + lane] = (_Float16)r1;
    }
    if (n2) {
        float s2 = r0 * r0 + r1 * r1;
#pragma unroll
        for (int o = 32; o > 0; o >>= 1) s2 += __shfl_xor(s2, o);
        if (lane == 0) n2[node] = s2;
    }
}

// ---------- MFMA KNN scan ----------
__global__ __launch_bounds__(256) void k_knn_scan(
    const _Float16* __restrict__ hr2, const _Float16* __restrict__ hc2,
    const float* __restrict__ nr2, int n_c, int n_r, int rs_chunk,
    int* __restrict__ cand_i) {
    __shared__ _Float16 lds[2][64 * HID];
    int t = threadIdx.x, w = t >> 6, lane = t & 63;
    int li = lane & 15, q = lane >> 4;
    int c0 = blockIdx.x * KNN_CB;
    int split = blockIdx.y;
    int rbeg = split * rs_chunk;
    int rows = min(rs_chunk, n_r - rbeg);
    int rend = rbeg + rows;

    if (rows <= 0) {
        int c = c0 + w * 16 + li;
        if (c < n_c) {
            size_t base = ((size_t)(c * CSPLIT + split) * 4 + q) * 3;
            for (int k = 0; k < 3; ++k) cand_i[base + k] = 0x7fffffff;
        }
        return;
    }

    // B fragments: collider col = li, k = ks*32 + q*8 .. +7
    f16x8 bf[4];
    {
        int c = c0 + w * 16 + li;
        int cc = min(c, n_c - 1);
#pragma unroll
        for (int ks = 0; ks < 4; ++ks)
            bf[ks] = *(const f16x8*)(hc2 + (size_t)cc * HID + ks * 32 + q * 8);
    }

    float bd[3]; int bi[3];
#pragma unroll
    for (int k = 0; k < 3; ++k) { bd[k] = INFINITY; bi[k] = 0x7fffffff; }

    int nch = (rows + 63) >> 6;

    auto STAGE = [&](int bsel, int R) {
#pragma unroll
        for (int j = 0; j < 4; ++j) {
            int row = w * 16 + j * 4 + q;
            int gr = min(R + row, n_r - 1);
            int sslot = li ^ (row & 7);
            const _Float16* src = hr2 + (size_t)gr * HID + sslot * 8;
            _Float16* dst = &lds[bsel][(w * 16 + j * 4) * HID];  // wave-uniform
            __builtin_amdgcn_global_load_lds(
                (const __attribute__((address_space(1))) void*)src,
                (__attribute__((address_space(3))) void*)dst, 16, 0, 0);
        }
    };

    STAGE(0, rbeg);
    __syncthreads();

    for (int ch = 0; ch < nch; ++ch) {
        int cur = ch & 1;
        if (ch + 1 < nch) STAGE(cur ^ 1, rbeg + (ch + 1) * 64);  // prefetch
        int R = rbeg + ch * 64;
        const _Float16* buf = lds[cur];
        if (R + 64 <= rend) {
            float4 nrv[4];
#pragma unroll
            for (int tt = 0; tt < 4; ++tt)
                nrv[tt] = *(const float4*)(nr2 + R + tt * 16 + q * 4);
#pragma unroll
            for (int tt = 0; tt < 4; ++tt) {
                f32x4 a0 = {0.f, 0.f, 0.f, 0.f};
                int lr = tt * 16 + li;
                int swr = lr & 7;
#pragma unroll
                for (int ks = 0; ks < 4; ++ks) {
                    f16x8 af = *(const f16x8*)(&buf[lr * HID + (((ks * 4 + q) ^ swr) << 3)]);
                    a0 = __builtin_amdgcn_mfma_f32_16x16x32_f16(af, bf[ks], a0, 0, 0, 0);
                }
                int r_base = R + tt * 16 + q * 4;
                float sv[4] = {nrv[tt].x, nrv[tt].y, nrv[tt].z, nrv[tt].w};
#pragma unroll
                for (int i = 0; i < 4; ++i)
                    ins3(sv[i] - 2.f * a0[i], r_base + i, bd, bi);
            }
        } else {
            int rows_rem = rend - R;
#pragma unroll
            for (int tt = 0; tt < 4; ++tt) {
                int br = tt * 16;
                if (br < rows_rem) {
                    f32x4 a0 = {0.f, 0.f, 0.f, 0.f};
                    int lr = br + li;
                    int swr = lr & 7;
#pragma unroll
                    for (int ks = 0; ks < 4; ++ks) {
                        f16x8 af = *(const f16x8*)(&buf[lr * HID + (((ks * 4 + q) ^ swr) << 3)]);
                        a0 = __builtin_amdgcn_mfma_f32_16x16x32_f16(af, bf[ks], a0, 0, 0, 0);
                    }
                    int r_base = R + br + q * 4;
                    float4 nrv = *(const float4*)(nr2 + r_base);
                    float sv[4] = {nrv.x, nrv.y, nrv.z, nrv.w};
#pragma unroll
                    for (int i = 0; i < 4; ++i) {
                        int r = r_base + i;
                        if (r < rend) ins3(sv[i] - 2.f * a0[i], r, bd, bi);
                    }
                }
            }
        }
        __syncthreads();
    }

    {
        int c = c0 + w * 16 + li;
        if (c < n_c) {
            size_t base = ((size_t)(c * CSPLIT + split) * 4 + q) * 3;
#pragma unroll
            for (int k = 0; k < 3; ++k) cand_i[base + k] = bi[k];
        }
    }
}

// ---------- exact rerank: block per collider -> top-3 indices (NO atomics) ---
__global__ __launch_bounds__(256, 4) void k_rerank(
    const int* __restrict__ cand_i, const float* __restrict__ hc,
    const float* __restrict__ hr, const float* __restrict__ nr2,
    int n_r, int* __restrict__ nn_idx) {
    int c = blockIdx.x;
    int t = threadIdx.x;
    __shared__ float hcs[HID];
    __shared__ int ci[NCAND];
    __shared__ float sc[NCAND];
    __shared__ int scr[NCAND];
    if (t < HID) hcs[t] = hc[(size_t)c * HID + t];
    if (t < NCAND) {
        int r = cand_i[(size_t)c * NCAND + t];
        ci[t] = ((unsigned)r < (unsigned)n_r) ? r : -1;
    }
    __syncthreads();

    int k4 = t & 31;
    int g = t >> 5;                                // 0..7
    const float4* hr4 = (const float4*)hr;
    float4 a = ((const float4*)hcs)[k4];

    int rj[12];
    float4 v[12];
#pragma unroll
    for (int p = 0; p < 12; ++p) {                 // issue all loads (MLP)
        rj[p] = ci[p * 8 + g];
        v[p] = hr4[(size_t)max(rj[p], 0) * 32 + k4];
    }
    float fd[3] = {INFINITY, INFINITY, INFINITY};
    int fi[3] = {0x7fffffff, 0x7fffffff, 0x7fffffff};
#pragma unroll
    for (int p = 0; p < 12; ++p) {
        float d = a.x * v[p].x + a.y * v[p].y + a.z * v[p].z + a.w * v[p].w;
#pragma unroll
        for (int o = 1; o < 32; o <<= 1) d += __shfl_xor(d, o);
        if (k4 == 0) {
            int j = p * 8 + g;
            sc[j] = (rj[p] >= 0) ? nr2[rj[p]] - 2.f * d : INFINITY;
            scr[j] = (rj[p] >= 0) ? rj[p] : 0x7fffffff;
        }
    }
    __syncthreads();
    if (t < 64) {
        ins3(sc[t], scr[t], fd, fi);
        if (t < 32) ins3(sc[64 + t], scr[64 + t], fd, fi);
#pragma unroll
        for (int o = 1; o < 64; o <<= 1) {
            float sd0 = __shfl_xor(fd[0], o), sd1 = __shfl_xor(fd[1], o), sd2 = __shfl_xor(fd[2], o);
            int si0 = __shfl_xor(fi[0], o), si1 = __shfl_xor(fi[1], o), si2 = __shfl_xor(fi[2], o);
            ins3(sd0, si0, fd, fi);
            ins3(sd1, si1, fd, fi);
            ins3(sd2, si2, fd, fi);
        }
        if (t == 0) {
            nn_idx[c * 3 + 0] = fi[0];
            nn_idx[c * 3 + 1] = fi[1];
            nn_idx[c * 3 + 2] = fi[2];
        }
    }
}

// ---------- pooled-mean + decode (wave per resting node, pure streaming) -----
__global__ __launch_bounds__(256) void k_pool_decode(
    const int* __restrict__ poff, const float* __restrict__ pooled,
    const float* __restrict__ hr, const float* __restrict__ Wd,
    const float* __restrict__ bd, float* __restrict__ out, int n) {
    int node = blockIdx.x * 4 + (threadIdx.x >> 6);
    int lane = threadIdx.x & 63;
    if (node >= n) return;                        // wave-uniform
    int len = poff[node + 1] - poff[node];
    float inv = 1.f / fmaxf((float)len, 1.f);
    float p0 = pooled[(size_t)node * HID + lane] * inv;
    float p1 = pooled[(size_t)node * HID + 64 + lane] * inv;
    float h0 = hr[(size_t)node * HID + lane];
    float h1 = hr[(size_t)node * HID + 64 + lane];
    float a0 = h0 * Wd[lane * 3 + 0] + h1 * Wd[(64 + lane) * 3 + 0]
             + p0 * Wd[(HID + lane) * 3 + 0] + p1 * Wd[(HID + 64 + lane) * 3 + 0];
    float a1 = h0 * Wd[lane * 3 + 1] + h1 * Wd[(64 + lane) * 3 + 1]
             + p0 * Wd[(HID + lane) * 3 + 1] + p1 * Wd[(HID + 64 + lane) * 3 + 1];
    float a2 = h0 * Wd[lane * 3 + 2] + h1 * Wd[(64 + lane) * 3 + 2]
             + p0 * Wd[(HID + lane) * 3 + 2] + p1 * Wd[(HID + 64 + lane) * 3 + 2];
#pragma unroll
    for (int o = 32; o > 0; o >>= 1) {
        a0 += __shfl_xor(a0, o);
        a1 += __shfl_xor(a1, o);
        a2 += __shfl_xor(a2, o);
    }
    if (lane == 0) {
        out[(size_t)node * 3 + 0] = a0 + bd[0];
        out[(size_t)node * 3 + 1] = a1 + bd[1];
        out[(size_t)node * 3 + 2] = a2 + bd[2];
    }
}

// ---------- launch ----------
static inline int cdiv(long long a, int b) { return (int)((a + b - 1) / b); }

extern "C" void kernel_launch(void* const* d_in, const int* in_sizes, int n_in,
                              void* d_out, int out_size, void* d_ws, size_t ws_size,
                              hipStream_t stream) {
    const float* x_r = (const float*)d_in[0];
    const float* x_c = (const float*)d_in[1];
    const int* ei_r = (const int*)d_in[2];
    const int* ei_c = (const int*)d_in[3];
    const float* W_r1 = (const float*)d_in[5];
    const float* as_r1 = (const float*)d_in[6];
    const float* ad_r1 = (const float*)d_in[7];
    const float* b_r1 = (const float*)d_in[8];
    const float* W_r2 = (const float*)d_in[9];
    const float* as_r2 = (const float*)d_in[10];
    const float* ad_r2 = (const float*)d_in[11];
    const float* b_r2 = (const float*)d_in[12];
    const float* W_c1 = (const float*)d_in[13];
    const float* as_c1 = (const float*)d_in[14];
    const float* ad_c1 = (const float*)d_in[15];
    const float* b_c1 = (const float*)d_in[16];
    const float* W_c2 = (const float*)d_in[17];
    const float* as_c2 = (const float*)d_in[18];
    const float* ad_c2 = (const float*)d_in[19];
    const float* b_c2 = (const float*)d_in[20];
    const float* W_dec = (const float*)d_in[21];
    const float* b_dec = (const float*)d_in[22];
    float* out = (float*)d_out;

    const int N_R = in_sizes[0] / 6;
    const int N_C = in_sizes[1] / 6;
    const int E_R = in_sizes[2] / 2;
    const int E_C = in_sizes[3] / 2;

    float* ws = (float*)d_ws;
    size_t off = 0;
    auto alloc = [&](size_t nf) {
        float* p = ws + off;
        off += (nf + 3) & ~(size_t)3;
        return p;
    };
    float* r_h    = alloc((size_t)N_R * HID);
    float* r_agg  = alloc((size_t)N_R * HID);
    float* c_h    = alloc((size_t)N_C * HID);
    float* c_agg  = alloc((size_t)N_C * HID);
    float* pooled = alloc((size_t)N_R * HID);
    float* r_es = alloc(N_R);
    float* r_ed = alloc(N_R);
    float* c_es = alloc(N_C);
    float* c_ed = alloc(N_C);
    float* nr2 = alloc((size_t)N_R + 512);
    _Float16* hr2 = (_Float16*)alloc((size_t)N_R * HID / 2);
    _Float16* hc2 = (_Float16*)alloc((size_t)N_C * HID / 2);
    int* cand_i = (int*)alloc((size_t)N_C * NCAND);
    int* nn_idx = (int*)alloc((size_t)N_C * 3);
    // CSR (resting)
    int* r_deg = (int*)alloc(N_R);
    int* r_off = (int*)alloc((size_t)N_R + 1);
    int* r_cur = (int*)alloc(N_R);
    int* r_csr = (int*)alloc((size_t)E_R + N_R);
    int* r_bsum = (int*)alloc(256);
    // CSR (collider)
    int* c_deg = (int*)alloc(N_C);
    int* c_off = (int*)alloc((size_t)N_C + 1);
    int* c_cur = (int*)alloc(N_C);
    int* c_csr = (int*)alloc((size_t)E_C + N_C);
    int* c_bsum = (int*)alloc(256);
    // NN pooling CSR + segments
    int* p_cnt = (int*)alloc(N_R);
    int* p_off = (int*)alloc((size_t)N_R + 1);
    int* p_cur = (int*)alloc(N_R);
    int* p_list = (int*)alloc((size_t)N_C * 3);
    int* p_bsum = (int*)alloc(256);
    int* s_cnt = (int*)alloc(4);
    int* s_node = (int*)alloc((size_t)N_C * 3 + 4096);
    int* s_off = (int*)alloc((size_t)N_C * 3 + 4096);
    (void)ws_size; (void)n_in; (void)out_size;

    auto build_csr = [&](const int* ei, int E, int n, int* deg, int* offp, int* cur,
                         int* csr, int* bsum) {
        hipMemsetAsync(deg, 0, (size_t)n * sizeof(int), stream);
        k_deg<<<cdiv(E + n, 256), 256, 0, stream>>>(ei, E, n, deg);
        int nb = cdiv(n, 256);
        k_chunksum<<<nb, 256, 0, stream>>>(deg, bsum, n);
        k_scan_small<<<1, 256, 0, stream>>>(bsum, nb);
        k_scan_apply<<<nb, 256, 0, stream>>>(deg, bsum, offp, cur, n);
        k_scatter<<<cdiv(E + n, 256), 256, 0, stream>>>(ei, E, n, cur, csr);
    };
    auto gat = [&](const float* x, int d_in_dim, int n, const int* offp, const int* csr,
                   const float* W, const float* as_, const float* ad_, const float* b,
                   float* h, float* es, float* ed, float* agg,
                   _Float16* h16, float* n2) {
        k_linear<<<cdiv(n, 4), 128, 0, stream>>>(x, W, as_, ad_, h, es, ed, d_in_dim, n);
        k_gat_csr<<<cdiv(n, 4), 256, 0, stream>>>(offp, csr, es, ed, h, b, agg, n, h16, n2);
    };

    // resting branch
    build_csr(ei_r, E_R, N_R, r_deg, r_off, r_cur, r_csr, r_bsum);
    gat(x_r, 6, N_R, r_off, r_csr, W_r1, as_r1, ad_r1, b_r1, r_h, r_es, r_ed, r_agg,
        nullptr, nullptr);
    gat(r_agg, HID, N_R, r_off, r_csr, W_r2, as_r2, ad_r2, b_r2, r_h, r_es, r_ed, r_agg,
        hr2, nr2);
    // collider branch
    build_csr(ei_c, E_C, N_C, c_deg, c_off, c_cur, c_csr, c_bsum);
    gat(x_c, 6, N_C, c_off, c_csr, W_c1, as_c1, ad_c1, b_c1, c_h, c_es, c_ed, c_agg,
        nullptr, nullptr);
    gat(c_agg, HID, N_C, c_off, c_csr, W_c2, as_c2, ad_c2, b_c2, c_h, c_es, c_ed, c_agg,
        hc2, nullptr);

    // MFMA candidate scan
    int RS = cdiv(N_R, CSPLIT * 64) * 64;
    dim3 sgrid(cdiv(N_C, KNN_CB), CSPLIT);
    k_knn_scan<<<sgrid, 256, 0, stream>>>(hr2, hc2, nr2, N_C, N_R, RS, cand_i);

    // exact rerank -> top-3 indices (no atomics)
    k_rerank<<<N_C, 256, 0, stream>>>(cand_i, c_agg, r_agg, nr2, N_R, nn_idx);

    // build pooling CSR + segment-parallel mean
    {
        int m = N_C * 3;
        hipMemsetAsync(p_cnt, 0, (size_t)N_R * sizeof(int), stream);
        k_nn_hist<<<cdiv(m, 256), 256, 0, stream>>>(nn_idx, m, N_R, p_cnt);
        int nb = cdiv(N_R, 256);
        k_chunksum<<<nb, 256, 0, stream>>>(p_cnt, p_bsum, N_R);
        k_scan_small<<<1, 256, 0, stream>>>(p_bsum, nb);
        k_scan_apply<<<nb, 256, 0, stream>>>(p_cnt, p_bsum, p_off, p_cur, N_R);
        k_nn_scatter<<<cdiv(m, 256), 256, 0, stream>>>(nn_idx, m, N_R, p_cur, p_list);
        // segment decomposition (hub-skew safe)
        hipMemsetAsync(s_cnt, 0, sizeof(int), stream);
        hipMemsetAsync(pooled, 0, (size_t)N_R * HID * sizeof(float), stream);
        k_build_segs<<<cdiv(N_R, 256), 256, 0, stream>>>(p_off, N_R, s_cnt, s_node, s_off);
        k_pool_seg<<<2048, 256, 0, stream>>>(s_cnt, s_node, s_off, p_off, p_list,
                                             c_agg, pooled);
    }

    // pooled-mean + decode (streaming)
    k_pool_decode<<<cdiv(N_R, 4), 256, 0, stream>>>(p_off, pooled, r_agg,
                                                    W_dec, b_dec, out, N_R);
}